// Round 5
// baseline (3033.592 us; speedup 1.0000x reference)
//
#include <hip/hip_runtime.h>
#include <hip/hip_bf16.h>
#include <math.h>

#define B_ 64
#define HB_ 32
#define L_ 57
#define D_ 512
#define H_ 8
#define DK_ 64
#define NC_ 2048

// ---------------- weight transpose: w[cout][cin][k] -> wT[cin*K + k][cout]
__global__ __launch_bounds__(256) void wtrans_k(const float* __restrict__ w,
                                                float* __restrict__ wT,
                                                int CINK, int COUT)
{
  int idx = blockIdx.x * 256 + threadIdx.x;
  if (idx >= CINK * COUT) return;
  int r = idx / COUT, c = idx - r * COUT;
  wT[idx] = w[(size_t)c * CINK + r];
}

// ---------------- conv-as-GEMM: y[b][c][t] = sum_r wT[r][c] * x[b][r/K][t*S + r%K]
// Block: 256 thr = 4 waves (2x2); tile CT cout x TT t; lane microtile MR x NR.
// Both operands staged in LDS (no SMEM in inner loop -> in-order lgkmcnt),
// double-buffered 16-row K-chunks.
template<int CIN, int K, int S, int COUT, int CT, int TT>
__global__ __launch_bounds__(256, 4) void gconv_k(
    const float* __restrict__ x, const float* __restrict__ wT,
    const float* __restrict__ bias, float* __restrict__ y,
    int Tin, int Tout)
{
  constexpr int CINK = CIN * K;
  constexpr int KC = 16;
  constexpr int NCH = (CINK + KC - 1) / KC;
  constexpr int MR = CT / 16, NR = TT / 16;
  constexpr int A4 = KC * CT / 4 / 256;   // float4 per thread, A stage
  constexpr int BE = KC * TT / 256;       // scalars per thread, B stage
  __shared__ __align__(16) float As[2][KC][CT];
  __shared__ __align__(16) float Bs[2][KC][TT];
  const int b   = blockIdx.z;
  const int ct0 = blockIdx.x * CT;
  const int t0  = blockIdx.y * TT;
  const int tid = threadIdx.x;
  const int wv = tid >> 6, lane = tid & 63;
  const int wm = wv >> 1, wn = wv & 1;
  const int lrow = lane >> 3, lcol = lane & 7;
  const int cA = wm * (CT / 2) + lrow * MR;   // tile-relative cout base
  const int cB = wn * (TT / 2) + lcol * NR;   // tile-relative t base
  const float* xb = x + (size_t)b * CIN * Tin;

  float acc[MR][NR];
#pragma unroll
  for (int i = 0; i < MR; ++i)
#pragma unroll
    for (int j = 0; j < NR; ++j) acc[i][j] = 0.f;

  auto stage = [&](int ch, int bi) {
    const int r0 = ch * KC;
#pragma unroll
    for (int i = 0; i < A4; ++i) {
      int f = tid + i * 256;
      int rr = f / (CT / 4), c4 = (f & (CT / 4 - 1)) * 4;
      float4 v = make_float4(0.f, 0.f, 0.f, 0.f);
      if (r0 + rr < CINK)
        v = *reinterpret_cast<const float4*>(&wT[(size_t)(r0 + rr) * COUT + ct0 + c4]);
      *reinterpret_cast<float4*>(&As[bi][rr][c4]) = v;
    }
#pragma unroll
    for (int i = 0; i < BE; ++i) {
      int e = tid + i * 256;
      int rr = e / TT, tt = e & (TT - 1);
      int r = r0 + rr;
      int cin = r / K, k = r - cin * K;
      int t = t0 + tt;
      float v = 0.f;
      if (r < CINK && t < Tout) v = xb[(size_t)cin * Tin + t * S + k];
      Bs[bi][rr][tt] = v;
    }
  };

  stage(0, 0);
  for (int ch = 0; ch < NCH; ++ch) {
    __syncthreads();
    if (ch + 1 < NCH) stage(ch + 1, (ch + 1) & 1);
    const int bi = ch & 1;
#pragma unroll
    for (int rr = 0; rr < KC; ++rr) {
      float a[MR], bb[NR];
#pragma unroll
      for (int i = 0; i < MR; i += 4)
        *reinterpret_cast<float4*>(&a[i]) = *reinterpret_cast<const float4*>(&As[bi][rr][cA + i]);
#pragma unroll
      for (int j = 0; j < NR; j += 4)
        *reinterpret_cast<float4*>(&bb[j]) = *reinterpret_cast<const float4*>(&Bs[bi][rr][cB + j]);
#pragma unroll
      for (int i = 0; i < MR; ++i)
#pragma unroll
        for (int j = 0; j < NR; ++j)
          acc[i][j] += a[i] * bb[j];
    }
  }

#pragma unroll
  for (int i = 0; i < MR; ++i) {
    int c = ct0 + cA + i;
    float bv = bias[c];
    float* yr = y + ((size_t)b * COUT + c) * Tout;
#pragma unroll
    for (int j = 0; j < NR; ++j) {
      int t = t0 + cB + j;
      if (t < Tout) yr[t] = acc[i][j] + bv;
    }
  }
}

// ---------------- transpose c6 [B,512,57] -> xT [B,57,512]
__global__ __launch_bounds__(256) void transpose_k(const float* __restrict__ c6,
                                                   float* __restrict__ xT)
{
  const int b = blockIdx.y, dt = blockIdx.x;  // 16 tiles of 32 d
  __shared__ float tile[32 * 58];
  const int tid = threadIdx.x;
  const int d0 = dt * 32;
  for (int e = tid; e < 32 * L_; e += 256) {
    int dd = e / L_, l = e - dd * L_;
    tile[dd * 58 + l] = c6[((size_t)b * D_ + d0 + dd) * L_ + l];
  }
  __syncthreads();
  for (int e = tid; e < L_ * 32; e += 256) {
    int l = e >> 5, dd = e & 31;
    xT[((size_t)b * L_ + l) * D_ + d0 + dd] = tile[dd * 58 + l];
  }
}

// ---------------- inverse transpose yattn [B,57,512] -> yT [B,512,57]
__global__ __launch_bounds__(256) void itranspose_k(const float* __restrict__ y,
                                                    float* __restrict__ yT)
{
  const int b = blockIdx.y, dt = blockIdx.x;  // 16 tiles of 32 d
  __shared__ float tile[32 * 58];
  const int tid = threadIdx.x;
  const int d0 = dt * 32;
  for (int e = tid; e < L_ * 32; e += 256) {
    int l = e >> 5, dd = e & 31;
    tile[dd * 58 + l] = y[((size_t)b * L_ + l) * D_ + d0 + dd];
  }
  __syncthreads();
  for (int e = tid; e < 32 * L_; e += 256) {
    int dd = e / L_, l = e - dd * L_;
    yT[((size_t)b * D_ + d0 + dd) * L_ + l] = tile[dd * 58 + l];
  }
}

// ---------------- fused QKV projection: out[b,h,l,kd] for q,k,v
__global__ __launch_bounds__(256) void qkv3_k(
    const float* __restrict__ xT, const float* __restrict__ wq,
    const float* __restrict__ wk, const float* __restrict__ wv,
    float* __restrict__ q, float* __restrict__ k, float* __restrict__ v)
{
  const int b = blockIdx.y;
  const int ot = blockIdx.x >> 2;
  const int lt = blockIdx.x & 3;
  const int l0 = lt * 16;
  __shared__ __align__(16) float cs[16 * D_];
  const int tid = threadIdx.x;
  for (int e = tid; e < 16 * D_; e += 256) {
    int l = l0 + (e >> 9);
    cs[e] = (l < L_) ? xT[((size_t)b * L_ + l) * D_ + (e & 511)] : 0.f;
  }
  __syncthreads();
  const int o3 = ot * 256 + tid;
  const int set = o3 >> 9;            // uniform per block
  const int oo = o3 & 511;
  const int h = oo >> 6, kd = oo & 63;
  const float* W = (set == 0 ? wq : (set == 1 ? wk : wv));
  const float* wp = W + (size_t)h * D_ * DK_ + kd;
  float acc[16];
#pragma unroll
  for (int j = 0; j < 16; ++j) acc[j] = 0.f;
  for (int d = 0; d < D_; d += 4) {
    float w0 = wp[(size_t)d * DK_];
    float w1 = wp[(size_t)(d + 1) * DK_];
    float w2 = wp[(size_t)(d + 2) * DK_];
    float w3 = wp[(size_t)(d + 3) * DK_];
#pragma unroll
    for (int j = 0; j < 16; ++j) {
      const float4 c4 = *reinterpret_cast<const float4*>(&cs[j * D_ + d]);
      acc[j] += c4.x * w0 + c4.y * w1 + c4.z * w2 + c4.w * w3;
    }
  }
  float* OUT = (set == 0 ? q : (set == 1 ? k : v));
#pragma unroll
  for (int j = 0; j < 16; ++j) {
    int l = l0 + j;
    if (l < L_) OUT[(((size_t)b * H_ + h) * L_ + l) * DK_ + kd] = acc[j];
  }
}

// ---------------- attention per (b,h); writes concat layout cat[b][l][h*64+kd]
__global__ __launch_bounds__(256) void attn_k(
    const float* __restrict__ q, const float* __restrict__ k, const float* __restrict__ v,
    float* __restrict__ cat)
{
  const int bh = blockIdx.x;
  const int b = bh >> 3, h = bh & 7;
  __shared__ float qs[L_ * DK_];
  __shared__ float ks[L_ * 65];      // padded: kills 32-way bank conflict
  __shared__ float vs[L_ * DK_];
  __shared__ float ps[L_ * DK_];
  const int tid = threadIdx.x;
  const float* qb = q + (size_t)bh * L_ * DK_;
  const float* kb = k + (size_t)bh * L_ * DK_;
  const float* vb = v + (size_t)bh * L_ * DK_;
  for (int e = tid; e < L_ * DK_; e += 256) {
    qs[e] = qb[e];
    vs[e] = vb[e];
    int m = e >> 6, d = e & 63;
    ks[m * 65 + d] = kb[e];
  }
  __syncthreads();
  for (int e = tid; e < L_ * L_; e += 256) {
    int l = e / L_, m = e - (e / L_) * L_;
    float s = 0.f;
#pragma unroll
    for (int d = 0; d < DK_; ++d) s += qs[l * DK_ + d] * ks[m * 65 + d];
    ps[l * DK_ + m] = s * 0.125f;
  }
  __syncthreads();
  if (tid < L_) {
    float mx = -1e30f;
    for (int m = 0; m < L_; ++m) mx = fmaxf(mx, ps[tid * DK_ + m]);
    float sum = 0.f;
    for (int m = 0; m < L_; ++m) { float e2 = __expf(ps[tid * DK_ + m] - mx); ps[tid * DK_ + m] = e2; sum += e2; }
    float inv = 1.f / sum;
    for (int m = 0; m < L_; ++m) ps[tid * DK_ + m] *= inv;
  }
  __syncthreads();
  for (int e = tid; e < L_ * DK_; e += 256) {
    int l = e >> 6, kd = e & 63;
    float s = 0.f;
    for (int m = 0; m < L_; ++m) s += ps[l * DK_ + m] * vs[m * DK_ + kd];
    cat[((size_t)b * L_ + l) * D_ + h * DK_ + kd] = s;
  }
}

// ---------------- output projection: y[b,l,o] = cat[b,l,:] @ wo + bo
__global__ __launch_bounds__(256) void outproj_k(
    const float* __restrict__ cat, const float* __restrict__ wo,
    const float* __restrict__ bo, float* __restrict__ y)
{
  const int b = blockIdx.y, lt = blockIdx.x;
  const int l0 = lt * 16;
  __shared__ __align__(16) float cs[16 * D_];
  const int tid = threadIdx.x;
  for (int e = tid; e < 16 * D_; e += 256) {
    int l = l0 + (e >> 9);
    cs[e] = (l < L_) ? cat[((size_t)b * L_ + l) * D_ + (e & 511)] : 0.f;
  }
  __syncthreads();
  float acc0[16], acc1[16];
#pragma unroll
  for (int j = 0; j < 16; ++j) { acc0[j] = 0.f; acc1[j] = 0.f; }
  for (int d = 0; d < D_; d += 4) {
    float w00 = wo[(size_t)d * D_ + tid];
    float w01 = wo[(size_t)(d + 1) * D_ + tid];
    float w02 = wo[(size_t)(d + 2) * D_ + tid];
    float w03 = wo[(size_t)(d + 3) * D_ + tid];
    float w10 = wo[(size_t)d * D_ + tid + 256];
    float w11 = wo[(size_t)(d + 1) * D_ + tid + 256];
    float w12 = wo[(size_t)(d + 2) * D_ + tid + 256];
    float w13 = wo[(size_t)(d + 3) * D_ + tid + 256];
#pragma unroll
    for (int j = 0; j < 16; ++j) {
      const float4 c4 = *reinterpret_cast<const float4*>(&cs[j * D_ + d]);
      acc0[j] += c4.x * w00 + c4.y * w01 + c4.z * w02 + c4.w * w03;
      acc1[j] += c4.x * w10 + c4.y * w11 + c4.z * w12 + c4.w * w13;
    }
  }
#pragma unroll
  for (int j = 0; j < 16; ++j) {
    int l = l0 + j;
    if (l < L_) {
      y[((size_t)b * L_ + l) * D_ + tid] = acc0[j] + bo[tid];
      y[((size_t)b * L_ + l) * D_ + tid + 256] = acc1[j] + bo[tid + 256];
    }
  }
}

// ---------------- codebook prep: transpose to [d][n] + norms
__global__ __launch_bounds__(64) void cbprep_k(const float* __restrict__ cb,
                                               float* __restrict__ cbT,
                                               float* __restrict__ cnorm)
{
  const int n = blockIdx.x, t = threadIdx.x;
  float s = 0.f;
  for (int d = t; d < D_; d += 64) {
    float vv = cb[(size_t)n * D_ + d];
    cbT[(size_t)d * NC_ + n] = vv;
    s += vv * vv;
  }
#pragma unroll
  for (int off = 32; off >= 1; off >>= 1) s += __shfl_xor(s, off);
  if (t == 0) cnorm[n] = s;
}

// ---------------- VQ distance GEMM + partial argmin (unchanged from round 4)
__global__ __launch_bounds__(256, 2) void vqgemm_k(
    const float* __restrict__ yT, const float* __restrict__ cbT,
    const float* __restrict__ cnorm, float* __restrict__ pmin, int* __restrict__ pidx)
{
  const int b = blockIdx.y, nt = blockIdx.x;
  const int tid = threadIdx.x;
  const int w = tid >> 6, lane = tid & 63;
  const int lrow = lane >> 3, ncol = lane & 7;
  __shared__ __align__(16) float As[32 * 68];
  __shared__ __align__(16) float Bs[32 * 256];
  __shared__ float redv[4][64];
  __shared__ int   redi[4][64];
  float acc[8][8];
#pragma unroll
  for (int li = 0; li < 8; ++li)
#pragma unroll
    for (int nj = 0; nj < 8; ++nj) acc[li][nj] = 0.f;

  const float* yTb = yT + (size_t)b * D_ * L_;
  const int n0 = nt * 256;
  const int nbase = n0 + w * 64 + ncol * 8;

  for (int d0 = 0; d0 < D_; d0 += 32) {
    __syncthreads();
#pragma unroll
    for (int i = 0; i < 8; ++i) {
      int e = tid + i * 256;
      int dd = e >> 6, l = e & 63;
      As[dd * 68 + l] = (l < L_) ? yTb[(size_t)(d0 + dd) * L_ + l] : 0.f;
    }
#pragma unroll
    for (int i = 0; i < 8; ++i) {
      int e = tid + i * 256;
      int dd = e >> 6, n4 = (e & 63) * 4;
      *reinterpret_cast<float4*>(&Bs[dd * 256 + n4]) =
          *reinterpret_cast<const float4*>(&cbT[(size_t)(d0 + dd) * NC_ + n0 + n4]);
    }
    __syncthreads();
#pragma unroll 4
    for (int dd = 0; dd < 32; ++dd) {
      float a8[8], b8[8];
      *reinterpret_cast<float4*>(&a8[0]) = *reinterpret_cast<const float4*>(&As[dd * 68 + lrow * 8]);
      *reinterpret_cast<float4*>(&a8[4]) = *reinterpret_cast<const float4*>(&As[dd * 68 + lrow * 8 + 4]);
      *reinterpret_cast<float4*>(&b8[0]) = *reinterpret_cast<const float4*>(&Bs[dd * 256 + w * 64 + ncol * 8]);
      *reinterpret_cast<float4*>(&b8[4]) = *reinterpret_cast<const float4*>(&Bs[dd * 256 + w * 64 + ncol * 8 + 4]);
#pragma unroll
      for (int li = 0; li < 8; ++li)
#pragma unroll
        for (int nj = 0; nj < 8; ++nj)
          acc[li][nj] += a8[li] * b8[nj];
    }
  }

  float cn[8];
  *reinterpret_cast<float4*>(&cn[0]) = *reinterpret_cast<const float4*>(&cnorm[nbase]);
  *reinterpret_cast<float4*>(&cn[4]) = *reinterpret_cast<const float4*>(&cnorm[nbase + 4]);
#pragma unroll
  for (int li = 0; li < 8; ++li) {
    float vb = cn[0] - 2.f * acc[li][0];
    int ib = nbase;
#pragma unroll
    for (int nj = 1; nj < 8; ++nj) {
      float v = cn[nj] - 2.f * acc[li][nj];
      if (v < vb) { vb = v; ib = nbase + nj; }
    }
#pragma unroll
    for (int off = 1; off <= 4; off <<= 1) {
      float vo = __shfl_xor(vb, off);
      int io = __shfl_xor(ib, off);
      if (vo < vb || (vo == vb && io < ib)) { vb = vo; ib = io; }
    }
    if (ncol == 0) { redv[w][lrow * 8 + li] = vb; redi[w][lrow * 8 + li] = ib; }
  }
  __syncthreads();
  if (tid < L_) {
    float vb = redv[0][tid]; int ib = redi[0][tid];
#pragma unroll
    for (int w2 = 1; w2 < 4; ++w2) {
      float vo = redv[w2][tid]; int io = redi[w2][tid];
      if (vo < vb || (vo == vb && io < ib)) { vb = vo; ib = io; }
    }
    pmin[((size_t)b * L_ + tid) * 8 + nt] = vb;
    pidx[((size_t)b * L_ + tid) * 8 + nt] = ib;
  }
}

// ---------------- VQ final: pick global argmin, emit z_q + index + loss partial
__global__ __launch_bounds__(64) void vqfin_k(
    const float* __restrict__ y, const float* __restrict__ cbook,
    const float* __restrict__ pmin, const int* __restrict__ pidx,
    float* __restrict__ zq, float* __restrict__ oidx, float* __restrict__ lpart)
{
  const int bl = blockIdx.x;
  const int tid = threadIdx.x;
  __shared__ int sidx;
  if (tid == 0) {
    float vb = pmin[(size_t)bl * 8];
    int ib = pidx[(size_t)bl * 8];
    for (int ntv = 1; ntv < 8; ++ntv) {
      float vo = pmin[(size_t)bl * 8 + ntv];
      int io = pidx[(size_t)bl * 8 + ntv];
      if (vo < vb || (vo == vb && io < ib)) { vb = vo; ib = io; }
    }
    sidx = ib;
  }
  __syncthreads();
  const int idx = sidx;
  const float* crow = cbook + (size_t)idx * D_;
  const float* yrow = y + (size_t)bl * D_;
  float s = 0.f;
  for (int d = tid; d < D_; d += 64) {
    float c = crow[d];
    float df = c - yrow[d];
    zq[(size_t)bl * D_ + d] = c;
    s += df * df;
  }
#pragma unroll
  for (int off = 32; off >= 1; off >>= 1) s += __shfl_xor(s, off);
  if (tid == 0) { lpart[bl] = s; oidx[bl] = (float)idx; }
}

// ---------------- loss reduce (deterministic fixed-order)
__global__ __launch_bounds__(256) void loss_k(const float* __restrict__ lpart,
                                              float* __restrict__ outLoss)
{
  const int tid = threadIdx.x;
  float s = 0.f;
  for (int i = tid; i < B_ * L_; i += 256) s += lpart[i];
  __shared__ float red[256];
  red[tid] = s;
  __syncthreads();
  for (int off = 128; off >= 1; off >>= 1) {
    if (tid < off) red[tid] += red[tid + off];
    __syncthreads();
  }
  if (tid == 0) outLoss[0] = red[0] * ((1.f + 0.2f) / (float)((size_t)B_ * L_ * D_));
}

extern "C" void kernel_launch(void* const* d_in, const int* in_sizes, int n_in,
                              void* d_out, int out_size, void* d_ws, size_t ws_size,
                              hipStream_t stream)
{
  const float* x  = (const float*)d_in[0];
  const float* w1 = (const float*)d_in[1];  const float* b1 = (const float*)d_in[2];
  const float* w2 = (const float*)d_in[3];  const float* b2 = (const float*)d_in[4];
  const float* w3 = (const float*)d_in[5];  const float* b3 = (const float*)d_in[6];
  const float* w4 = (const float*)d_in[7];  const float* b4 = (const float*)d_in[8];
  const float* w5 = (const float*)d_in[9];  const float* b5 = (const float*)d_in[10];
  const float* w6 = (const float*)d_in[11]; const float* b6 = (const float*)d_in[12];
  const float* wq = (const float*)d_in[13];
  const float* wk = (const float*)d_in[14];
  const float* wv = (const float*)d_in[15];
  const float* wo = (const float*)d_in[16];
  const float* bo = (const float*)d_in[17];
  const float* cbook = (const float*)d_in[18];

  float* ws = (float*)d_ws;
  // ---- Workspace layout (floats), peak ~12.32M (~49.3MB) — unchanged ----
  float* wT1 = ws;                  // 67,200
  float* wT2 = ws + 67200;          // 24,576
  float* wT3 = ws + 91776;          // 98,304
  float* wT4 = ws + 190080;         // 393,216
  float* wT5 = ws + 583296;         // 524,288
  float* wT6 = ws + 1107584;        // 524,288 -> ends 1,631,872
  float* bufA = ws + 1632000;       // 3,750,016
  float* bufB = ws + 5382016;       // 3,750,016
  float* c6   = ws + 9132032;       // 1,867,776
  // post-conv reuse (stream-serialized):
  float* qb    = ws;                // 1,867,776 (wT dead after convs)
  float* kb    = ws + 1867776;
  float* vb    = ws + 3735552;
  float* xT    = ws + 5603328;
  float* cat   = ws + 7471104;
  float* yattn = ws + 9338880;      // (c6 dead)
  float* cbT   = ws + 11206656;     // 1,048,576
  float* cnorm = ws + 12255232;     // 2,048
  float* pminb = ws + 12257280;     // 29,184
  int*   pidxb = (int*)(ws + 12286464); // 29,184
  float* lpart = ws + 12315648;     // 3,648
  float* yT    = ws;                // 1,867,776 (qb dead after attn_k)

  float* zq      = (float*)d_out;
  float* outLoss = zq + (size_t)B_ * L_ * D_;
  float* outIdx  = outLoss + 1;

  // weight re-layouts
  wtrans_k<<<(1050 * 64 + 255) / 256, 256, 0, stream>>>(w1, wT1, 1050, 64);
  wtrans_k<<<( 192 * 128 + 255) / 256, 256, 0, stream>>>(w2, wT2, 192, 128);
  wtrans_k<<<( 384 * 256 + 255) / 256, 256, 0, stream>>>(w3, wT3, 384, 256);
  wtrans_k<<<( 768 * 512 + 255) / 256, 256, 0, stream>>>(w4, wT4, 768, 512);
  wtrans_k<<<(1024 * 512 + 255) / 256, 256, 0, stream>>>(w5, wT5, 1024, 512);
  wtrans_k<<<(1024 * 512 + 255) / 256, 256, 0, stream>>>(w6, wT6, 1024, 512);

  // conv stack in two batch-halves of 32 (GEMM-formulated convs)
  for (int h = 0; h < 2; ++h) {
    const float* xh = x + (size_t)h * HB_ * 105 * 5500;
    float* c6h = c6 + (size_t)h * HB_ * D_ * L_;
    gconv_k<105,10,3, 64, 64,128><<<dim3(1,15,HB_),256,0,stream>>>(xh,   wT1,b1, bufA, 5500,1831);
    gconv_k< 64, 3,2,128,128, 64><<<dim3(1,15,HB_),256,0,stream>>>(bufA, wT2,b2, bufB, 1831, 915);
    gconv_k<128, 3,2,256,128, 64><<<dim3(2, 8,HB_),256,0,stream>>>(bufB, wT3,b3, bufA,  915, 457);
    gconv_k<256, 3,2,512,128, 64><<<dim3(4, 4,HB_),256,0,stream>>>(bufA, wT4,b4, bufB,  457, 228);
    gconv_k<512, 2,2,512,128, 64><<<dim3(4, 2,HB_),256,0,stream>>>(bufB, wT5,b5, bufA,  228, 114);
    gconv_k<512, 2,2,512,128, 64><<<dim3(4, 1,HB_),256,0,stream>>>(bufA, wT6,b6, c6h,  114,  57);
  }

  transpose_k<<<dim3(16, B_), 256, 0, stream>>>(c6, xT);
  qkv3_k<<<dim3(24, B_), 256, 0, stream>>>(xT, wq, wk, wv, qb, kb, vb);
  cbprep_k<<<NC_, 64, 0, stream>>>(cbook, cbT, cnorm);
  attn_k<<<B_ * H_, 256, 0, stream>>>(qb, kb, vb, cat);
  outproj_k<<<dim3(4, B_), 256, 0, stream>>>(cat, wo, bo, yattn);

  itranspose_k<<<dim3(16, B_), 256, 0, stream>>>(yattn, yT);
  vqgemm_k<<<dim3(8, B_), 256, 0, stream>>>(yT, cbT, cnorm, pminb, pidxb);
  vqfin_k<<<B_ * L_, 64, 0, stream>>>(yattn, cbook, pminb, pidxb, zq, outIdx, lpart);
  loss_k<<<1, 256, 0, stream>>>(lpart, outLoss);
}

// Round 6
// 1426.169 us; speedup vs baseline: 2.1271x; 2.1271x over previous
//
#include <hip/hip_runtime.h>
#include <hip/hip_bf16.h>
#include <math.h>

#define B_ 64
#define HB_ 32
#define L_ 57
#define D_ 512
#define H_ 8
#define DK_ 64
#define NC_ 2048

// ---------------- weight transpose: w[cout][cin][k] -> wT[cin*K + k][cout]
__global__ __launch_bounds__(256) void wtrans_k(const float* __restrict__ w,
                                                float* __restrict__ wT,
                                                int CINK, int COUT)
{
  int idx = blockIdx.x * 256 + threadIdx.x;
  if (idx >= CINK * COUT) return;
  int r = idx / COUT, c = idx - r * COUT;
  wT[idx] = w[(size_t)c * CINK + r];
}

// ---------------- conv1d (round-4 proven structure)
template<int CIN, int K, int S, int COUT, int CC>
__global__ __launch_bounds__(256) void conv1d_k(
    const float* __restrict__ x, const float* __restrict__ wT,
    const float* __restrict__ bias, float* __restrict__ y,
    int Tin, int Tout)
{
  constexpr int TT = 64;
  constexpr int SPAN = S * TT + K - S;   // <= 256 for all configs
  __shared__ float xs[CC * SPAN];
  const int b   = blockIdx.z;
  const int cbk = blockIdx.y;
  const int t0  = blockIdx.x * TT;
  const int tid = threadIdx.x;
  const int lane_t = tid & 63;
  const int g = tid >> 6;
  const int coutBase = __builtin_amdgcn_readfirstlane(cbk * 64 + g * 16);
  const int t = t0 + lane_t;
  float acc[16];
#pragma unroll
  for (int j = 0; j < 16; ++j) acc[j] = 0.f;
  const float* xb = x + (size_t)b * CIN * Tin;
  const int col0 = t0 * S;

  for (int c0 = 0; c0 < CIN; c0 += CC) {
    __syncthreads();
    for (int e = tid; e < CC * SPAN; e += 256) {
      int cc = e / SPAN, col = e - cc * SPAN;
      int ti = col0 + col;
      xs[e] = (ti < Tin) ? xb[(size_t)(c0 + cc) * Tin + ti] : 0.f;
    }
    __syncthreads();

    const float* wchunk = wT + ((size_t)c0 * K) * COUT + coutBase;
    for (int cc = 0; cc < CC; ++cc) {
#pragma unroll
      for (int kk = 0; kk < K; ++kk) {
        const float* wrow = wchunk + (size_t)(cc * K + kk) * COUT;
        float wv[16];
#pragma unroll
        for (int j = 0; j < 16; ++j) wv[j] = wrow[j];
        float xv = xs[cc * SPAN + lane_t * S + kk];
#pragma unroll
        for (int j = 0; j < 16; ++j) acc[j] += xv * wv[j];
      }
    }
  }
  if (t < Tout) {
#pragma unroll
    for (int j = 0; j < 16; ++j) {
      int co = coutBase + j;
      y[((size_t)b * COUT + co) * Tout + t] = acc[j] + bias[co];
    }
  }
}

// ---------------- K-split conv (same structure, partial sums, no bias)
// blockIdx.y: low 3 bits = cout block (COUT=512 -> 8), high bits = ks chunk.
template<int CINC, int K, int S, int COUT, int CC, int KS>
__global__ __launch_bounds__(256) void convks_k(
    const float* __restrict__ x, const float* __restrict__ wT,
    float* __restrict__ p, int Tin, int Tout, int bStrideX, int ksStrideP)
{
  constexpr int TT = 64;
  constexpr int SPAN = S * TT + K - S;
  __shared__ float xs[CC * SPAN];
  const int b   = blockIdx.z;
  const int cbk = blockIdx.y & 7;
  const int ks  = blockIdx.y >> 3;
  const int t0  = blockIdx.x * TT;
  const int tid = threadIdx.x;
  const int lane_t = tid & 63;
  const int g = tid >> 6;
  const int coutBase = __builtin_amdgcn_readfirstlane(cbk * 64 + g * 16);
  const int t = t0 + lane_t;
  float acc[16];
#pragma unroll
  for (int j = 0; j < 16; ++j) acc[j] = 0.f;
  const float* xb = x + (size_t)b * bStrideX + (size_t)ks * CINC * Tin;
  const float* wbase = wT + ((size_t)ks * CINC * K) * COUT;
  const int col0 = t0 * S;

  for (int c0 = 0; c0 < CINC; c0 += CC) {
    __syncthreads();
    for (int e = tid; e < CC * SPAN; e += 256) {
      int cc = e / SPAN, col = e - cc * SPAN;
      int ti = col0 + col;
      xs[e] = (ti < Tin) ? xb[(size_t)(c0 + cc) * Tin + ti] : 0.f;
    }
    __syncthreads();

    const float* wchunk = wbase + ((size_t)c0 * K) * COUT + coutBase;
    for (int cc = 0; cc < CC; ++cc) {
#pragma unroll
      for (int kk = 0; kk < K; ++kk) {
        const float* wrow = wchunk + (size_t)(cc * K + kk) * COUT;
        float wv[16];
#pragma unroll
        for (int j = 0; j < 16; ++j) wv[j] = wrow[j];
        float xv = xs[cc * SPAN + lane_t * S + kk];
#pragma unroll
        for (int j = 0; j < 16; ++j) acc[j] += xv * wv[j];
      }
    }
  }
  if (t < Tout) {
#pragma unroll
    for (int j = 0; j < 16; ++j) {
      int co = coutBase + j;
      p[(size_t)ks * ksStrideP + ((size_t)b * COUT + co) * Tout + t] = acc[j];
    }
  }
}

// ---------------- reduce K-split partials + bias (fixed ascending order)
template<int COUT, int TOUT, int KS>
__global__ __launch_bounds__(256) void redbias_k(
    const float* __restrict__ p, const float* __restrict__ bias,
    float* __restrict__ y, int ksStride, int n)
{
  int idx = blockIdx.x * 256 + threadIdx.x;
  if (idx >= n) return;
  int c = (idx / TOUT) % COUT;
  float s = p[idx];
#pragma unroll
  for (int ks = 1; ks < KS; ++ks) s += p[idx + (size_t)ks * ksStride];
  y[idx] = s + bias[c];
}

// ---------------- transpose c6 [B,512,57] -> xT [B,57,512]
__global__ __launch_bounds__(256) void transpose_k(const float* __restrict__ c6,
                                                   float* __restrict__ xT)
{
  const int b = blockIdx.y, dt = blockIdx.x;  // 16 tiles of 32 d
  __shared__ float tile[32 * 58];
  const int tid = threadIdx.x;
  const int d0 = dt * 32;
  for (int e = tid; e < 32 * L_; e += 256) {
    int dd = e / L_, l = e - dd * L_;
    tile[dd * 58 + l] = c6[((size_t)b * D_ + d0 + dd) * L_ + l];
  }
  __syncthreads();
  for (int e = tid; e < L_ * 32; e += 256) {
    int l = e >> 5, dd = e & 31;
    xT[((size_t)b * L_ + l) * D_ + d0 + dd] = tile[dd * 58 + l];
  }
}

// ---------------- inverse transpose yattn [B,57,512] -> yT [B,512,57]
__global__ __launch_bounds__(256) void itranspose_k(const float* __restrict__ y,
                                                    float* __restrict__ yT)
{
  const int b = blockIdx.y, dt = blockIdx.x;
  __shared__ float tile[32 * 58];
  const int tid = threadIdx.x;
  const int d0 = dt * 32;
  for (int e = tid; e < L_ * 32; e += 256) {
    int l = e >> 5, dd = e & 31;
    tile[dd * 58 + l] = y[((size_t)b * L_ + l) * D_ + d0 + dd];
  }
  __syncthreads();
  for (int e = tid; e < 32 * L_; e += 256) {
    int dd = e / L_, l = e - dd * L_;
    yT[((size_t)b * D_ + d0 + dd) * L_ + l] = tile[dd * 58 + l];
  }
}

// ---------------- fused QKV projection: out[b,h,l,kd] for q,k,v
__global__ __launch_bounds__(256) void qkv3_k(
    const float* __restrict__ xT, const float* __restrict__ wq,
    const float* __restrict__ wk, const float* __restrict__ wv,
    float* __restrict__ q, float* __restrict__ k, float* __restrict__ v)
{
  const int b = blockIdx.y;
  const int ot = blockIdx.x >> 2;
  const int lt = blockIdx.x & 3;
  const int l0 = lt * 16;
  __shared__ __align__(16) float cs[16 * D_];
  const int tid = threadIdx.x;
  for (int e = tid; e < 16 * D_; e += 256) {
    int l = l0 + (e >> 9);
    cs[e] = (l < L_) ? xT[((size_t)b * L_ + l) * D_ + (e & 511)] : 0.f;
  }
  __syncthreads();
  const int o3 = ot * 256 + tid;
  const int set = o3 >> 9;
  const int oo = o3 & 511;
  const int h = oo >> 6, kd = oo & 63;
  const float* W = (set == 0 ? wq : (set == 1 ? wk : wv));
  const float* wp = W + (size_t)h * D_ * DK_ + kd;
  float acc[16];
#pragma unroll
  for (int j = 0; j < 16; ++j) acc[j] = 0.f;
  for (int d = 0; d < D_; d += 4) {
    float w0 = wp[(size_t)d * DK_];
    float w1 = wp[(size_t)(d + 1) * DK_];
    float w2 = wp[(size_t)(d + 2) * DK_];
    float w3 = wp[(size_t)(d + 3) * DK_];
#pragma unroll
    for (int j = 0; j < 16; ++j) {
      const float4 c4 = *reinterpret_cast<const float4*>(&cs[j * D_ + d]);
      acc[j] += c4.x * w0 + c4.y * w1 + c4.z * w2 + c4.w * w3;
    }
  }
  float* OUT = (set == 0 ? q : (set == 1 ? k : v));
#pragma unroll
  for (int j = 0; j < 16; ++j) {
    int l = l0 + j;
    if (l < L_) OUT[(((size_t)b * H_ + h) * L_ + l) * DK_ + kd] = acc[j];
  }
}

// ---------------- attention per (b,h); writes concat layout cat[b][l][h*64+kd]
__global__ __launch_bounds__(256) void attn_k(
    const float* __restrict__ q, const float* __restrict__ k, const float* __restrict__ v,
    float* __restrict__ cat)
{
  const int bh = blockIdx.x;
  const int b = bh >> 3, h = bh & 7;
  __shared__ float qs[L_ * DK_];
  __shared__ float ks[L_ * 65];
  __shared__ float vs[L_ * DK_];
  __shared__ float ps[L_ * DK_];
  const int tid = threadIdx.x;
  const float* qb = q + (size_t)bh * L_ * DK_;
  const float* kb = k + (size_t)bh * L_ * DK_;
  const float* vb = v + (size_t)bh * L_ * DK_;
  for (int e = tid; e < L_ * DK_; e += 256) {
    qs[e] = qb[e];
    vs[e] = vb[e];
    int m = e >> 6, d = e & 63;
    ks[m * 65 + d] = kb[e];
  }
  __syncthreads();
  for (int e = tid; e < L_ * L_; e += 256) {
    int l = e / L_, m = e - (e / L_) * L_;
    float s = 0.f;
#pragma unroll
    for (int d = 0; d < DK_; ++d) s += qs[l * DK_ + d] * ks[m * 65 + d];
    ps[l * DK_ + m] = s * 0.125f;
  }
  __syncthreads();
  if (tid < L_) {
    float mx = -1e30f;
    for (int m = 0; m < L_; ++m) mx = fmaxf(mx, ps[tid * DK_ + m]);
    float sum = 0.f;
    for (int m = 0; m < L_; ++m) { float e2 = __expf(ps[tid * DK_ + m] - mx); ps[tid * DK_ + m] = e2; sum += e2; }
    float inv = 1.f / sum;
    for (int m = 0; m < L_; ++m) ps[tid * DK_ + m] *= inv;
  }
  __syncthreads();
  for (int e = tid; e < L_ * DK_; e += 256) {
    int l = e >> 6, kd = e & 63;
    float s = 0.f;
    for (int m = 0; m < L_; ++m) s += ps[l * DK_ + m] * vs[m * DK_ + kd];
    cat[((size_t)b * L_ + l) * D_ + h * DK_ + kd] = s;
  }
}

// ---------------- output projection: y[b,l,o] = cat[b,l,:] @ wo + bo
__global__ __launch_bounds__(256) void outproj_k(
    const float* __restrict__ cat, const float* __restrict__ wo,
    const float* __restrict__ bo, float* __restrict__ y)
{
  const int b = blockIdx.y, lt = blockIdx.x;
  const int l0 = lt * 16;
  __shared__ __align__(16) float cs[16 * D_];
  const int tid = threadIdx.x;
  for (int e = tid; e < 16 * D_; e += 256) {
    int l = l0 + (e >> 9);
    cs[e] = (l < L_) ? cat[((size_t)b * L_ + l) * D_ + (e & 511)] : 0.f;
  }
  __syncthreads();
  float acc0[16], acc1[16];
#pragma unroll
  for (int j = 0; j < 16; ++j) { acc0[j] = 0.f; acc1[j] = 0.f; }
  for (int d = 0; d < D_; d += 4) {
    float w00 = wo[(size_t)d * D_ + tid];
    float w01 = wo[(size_t)(d + 1) * D_ + tid];
    float w02 = wo[(size_t)(d + 2) * D_ + tid];
    float w03 = wo[(size_t)(d + 3) * D_ + tid];
    float w10 = wo[(size_t)d * D_ + tid + 256];
    float w11 = wo[(size_t)(d + 1) * D_ + tid + 256];
    float w12 = wo[(size_t)(d + 2) * D_ + tid + 256];
    float w13 = wo[(size_t)(d + 3) * D_ + tid + 256];
#pragma unroll
    for (int j = 0; j < 16; ++j) {
      const float4 c4 = *reinterpret_cast<const float4*>(&cs[j * D_ + d]);
      acc0[j] += c4.x * w00 + c4.y * w01 + c4.z * w02 + c4.w * w03;
      acc1[j] += c4.x * w10 + c4.y * w11 + c4.z * w12 + c4.w * w13;
    }
  }
#pragma unroll
  for (int j = 0; j < 16; ++j) {
    int l = l0 + j;
    if (l < L_) {
      y[((size_t)b * L_ + l) * D_ + tid] = acc0[j] + bo[tid];
      y[((size_t)b * L_ + l) * D_ + tid + 256] = acc1[j] + bo[tid + 256];
    }
  }
}

// ---------------- codebook prep: transpose to [d][n] + norms
__global__ __launch_bounds__(64) void cbprep_k(const float* __restrict__ cb,
                                               float* __restrict__ cbT,
                                               float* __restrict__ cnorm)
{
  const int n = blockIdx.x, t = threadIdx.x;
  float s = 0.f;
  for (int d = t; d < D_; d += 64) {
    float vv = cb[(size_t)n * D_ + d];
    cbT[(size_t)d * NC_ + n] = vv;
    s += vv * vv;
  }
#pragma unroll
  for (int off = 32; off >= 1; off >>= 1) s += __shfl_xor(s, off);
  if (t == 0) cnorm[n] = s;
}

// ---------------- VQ distance GEMM + partial argmin
__global__ __launch_bounds__(256, 2) void vqgemm_k(
    const float* __restrict__ yT, const float* __restrict__ cbT,
    const float* __restrict__ cnorm, float* __restrict__ pmin, int* __restrict__ pidx)
{
  const int b = blockIdx.y, nt = blockIdx.x;
  const int tid = threadIdx.x;
  const int w = tid >> 6, lane = tid & 63;
  const int lrow = lane >> 3, ncol = lane & 7;
  __shared__ __align__(16) float As[32 * 68];
  __shared__ __align__(16) float Bs[32 * 256];
  __shared__ float redv[4][64];
  __shared__ int   redi[4][64];
  float acc[8][8];
#pragma unroll
  for (int li = 0; li < 8; ++li)
#pragma unroll
    for (int nj = 0; nj < 8; ++nj) acc[li][nj] = 0.f;

  const float* yTb = yT + (size_t)b * D_ * L_;
  const int n0 = nt * 256;
  const int nbase = n0 + w * 64 + ncol * 8;

  for (int d0 = 0; d0 < D_; d0 += 32) {
    __syncthreads();
#pragma unroll
    for (int i = 0; i < 8; ++i) {
      int e = tid + i * 256;
      int dd = e >> 6, l = e & 63;
      As[dd * 68 + l] = (l < L_) ? yTb[(size_t)(d0 + dd) * L_ + l] : 0.f;
    }
#pragma unroll
    for (int i = 0; i < 8; ++i) {
      int e = tid + i * 256;
      int dd = e >> 6, n4 = (e & 63) * 4;
      *reinterpret_cast<float4*>(&Bs[dd * 256 + n4]) =
          *reinterpret_cast<const float4*>(&cbT[(size_t)(d0 + dd) * NC_ + n0 + n4]);
    }
    __syncthreads();
#pragma unroll 4
    for (int dd = 0; dd < 32; ++dd) {
      float a8[8], b8[8];
      *reinterpret_cast<float4*>(&a8[0]) = *reinterpret_cast<const float4*>(&As[dd * 68 + lrow * 8]);
      *reinterpret_cast<float4*>(&a8[4]) = *reinterpret_cast<const float4*>(&As[dd * 68 + lrow * 8 + 4]);
      *reinterpret_cast<float4*>(&b8[0]) = *reinterpret_cast<const float4*>(&Bs[dd * 256 + w * 64 + ncol * 8]);
      *reinterpret_cast<float4*>(&b8[4]) = *reinterpret_cast<const float4*>(&Bs[dd * 256 + w * 64 + ncol * 8 + 4]);
#pragma unroll
      for (int li = 0; li < 8; ++li)
#pragma unroll
        for (int nj = 0; nj < 8; ++nj)
          acc[li][nj] += a8[li] * b8[nj];
    }
  }

  float cn[8];
  *reinterpret_cast<float4*>(&cn[0]) = *reinterpret_cast<const float4*>(&cnorm[nbase]);
  *reinterpret_cast<float4*>(&cn[4]) = *reinterpret_cast<const float4*>(&cnorm[nbase + 4]);
#pragma unroll
  for (int li = 0; li < 8; ++li) {
    float vb = cn[0] - 2.f * acc[li][0];
    int ib = nbase;
#pragma unroll
    for (int nj = 1; nj < 8; ++nj) {
      float v = cn[nj] - 2.f * acc[li][nj];
      if (v < vb) { vb = v; ib = nbase + nj; }
    }
#pragma unroll
    for (int off = 1; off <= 4; off <<= 1) {
      float vo = __shfl_xor(vb, off);
      int io = __shfl_xor(ib, off);
      if (vo < vb || (vo == vb && io < ib)) { vb = vo; ib = io; }
    }
    if (ncol == 0) { redv[w][lrow * 8 + li] = vb; redi[w][lrow * 8 + li] = ib; }
  }
  __syncthreads();
  if (tid < L_) {
    float vb = redv[0][tid]; int ib = redi[0][tid];
#pragma unroll
    for (int w2 = 1; w2 < 4; ++w2) {
      float vo = redv[w2][tid]; int io = redi[w2][tid];
      if (vo < vb || (vo == vb && io < ib)) { vb = vo; ib = io; }
    }
    pmin[((size_t)b * L_ + tid) * 8 + nt] = vb;
    pidx[((size_t)b * L_ + tid) * 8 + nt] = ib;
  }
}

// ---------------- VQ final: pick global argmin, emit z_q + index + loss partial
__global__ __launch_bounds__(64) void vqfin_k(
    const float* __restrict__ y, const float* __restrict__ cbook,
    const float* __restrict__ pmin, const int* __restrict__ pidx,
    float* __restrict__ zq, float* __restrict__ oidx, float* __restrict__ lpart)
{
  const int bl = blockIdx.x;
  const int tid = threadIdx.x;
  __shared__ int sidx;
  if (tid == 0) {
    float vb = pmin[(size_t)bl * 8];
    int ib = pidx[(size_t)bl * 8];
    for (int ntv = 1; ntv < 8; ++ntv) {
      float vo = pmin[(size_t)bl * 8 + ntv];
      int io = pidx[(size_t)bl * 8 + ntv];
      if (vo < vb || (vo == vb && io < ib)) { vb = vo; ib = io; }
    }
    sidx = ib;
  }
  __syncthreads();
  const int idx = sidx;
  const float* crow = cbook + (size_t)idx * D_;
  const float* yrow = y + (size_t)bl * D_;
  float s = 0.f;
  for (int d = tid; d < D_; d += 64) {
    float c = crow[d];
    float df = c - yrow[d];
    zq[(size_t)bl * D_ + d] = c;
    s += df * df;
  }
#pragma unroll
  for (int off = 32; off >= 1; off >>= 1) s += __shfl_xor(s, off);
  if (tid == 0) { lpart[bl] = s; oidx[bl] = (float)idx; }
}

// ---------------- loss reduce (deterministic fixed-order)
__global__ __launch_bounds__(256) void loss_k(const float* __restrict__ lpart,
                                              float* __restrict__ outLoss)
{
  const int tid = threadIdx.x;
  float s = 0.f;
  for (int i = tid; i < B_ * L_; i += 256) s += lpart[i];
  __shared__ float red[256];
  red[tid] = s;
  __syncthreads();
  for (int off = 128; off >= 1; off >>= 1) {
    if (tid < off) red[tid] += red[tid + off];
    __syncthreads();
  }
  if (tid == 0) outLoss[0] = red[0] * ((1.f + 0.2f) / (float)((size_t)B_ * L_ * D_));
}

extern "C" void kernel_launch(void* const* d_in, const int* in_sizes, int n_in,
                              void* d_out, int out_size, void* d_ws, size_t ws_size,
                              hipStream_t stream)
{
  const float* x  = (const float*)d_in[0];
  const float* w1 = (const float*)d_in[1];  const float* b1 = (const float*)d_in[2];
  const float* w2 = (const float*)d_in[3];  const float* b2 = (const float*)d_in[4];
  const float* w3 = (const float*)d_in[5];  const float* b3 = (const float*)d_in[6];
  const float* w4 = (const float*)d_in[7];  const float* b4 = (const float*)d_in[8];
  const float* w5 = (const float*)d_in[9];  const float* b5 = (const float*)d_in[10];
  const float* w6 = (const float*)d_in[11]; const float* b6 = (const float*)d_in[12];
  const float* wq = (const float*)d_in[13];
  const float* wk = (const float*)d_in[14];
  const float* wv = (const float*)d_in[15];
  const float* wo = (const float*)d_in[16];
  const float* bo = (const float*)d_in[17];
  const float* cbook = (const float*)d_in[18];

  float* ws = (float*)d_ws;
  // ---- Workspace layout (floats), peak ~12.32M (~49.3MB) — unchanged ----
  float* wT1 = ws;                  // 67,200
  float* wT2 = ws + 67200;          // 24,576
  float* wT3 = ws + 91776;          // 98,304
  float* wT4 = ws + 190080;         // 393,216
  float* wT5 = ws + 583296;         // 524,288
  float* wT6 = ws + 1107584;        // 524,288 -> ends 1,631,872
  float* bufA = ws + 1632000;       // 3,750,016
  float* bufB = ws + 5382016;       // 3,750,016
  float* c6   = ws + 9132032;       // 1,867,776
  // post-conv reuse (stream-serialized):
  float* qb    = ws;                // 1,867,776 (wT dead after convs)
  float* kb    = ws + 1867776;
  float* vb    = ws + 3735552;
  float* xT    = ws + 5603328;
  float* cat   = ws + 7471104;
  float* yattn = ws + 9338880;      // (c6 dead)
  float* cbT   = ws + 11206656;     // 1,048,576
  float* cnorm = ws + 12255232;     // 2,048
  float* pminb = ws + 12257280;     // 29,184
  int*   pidxb = (int*)(ws + 12286464); // 29,184
  float* lpart = ws + 12315648;     // 3,648
  float* yT    = ws;                // 1,867,776 (qb dead after attn_k)

  float* zq      = (float*)d_out;
  float* outLoss = zq + (size_t)B_ * L_ * D_;
  float* outIdx  = outLoss + 1;

  // weight re-layouts
  wtrans_k<<<(1050 * 64 + 255) / 256, 256, 0, stream>>>(w1, wT1, 1050, 64);
  wtrans_k<<<( 192 * 128 + 255) / 256, 256, 0, stream>>>(w2, wT2, 192, 128);
  wtrans_k<<<( 384 * 256 + 255) / 256, 256, 0, stream>>>(w3, wT3, 384, 256);
  wtrans_k<<<( 768 * 512 + 255) / 256, 256, 0, stream>>>(w4, wT4, 768, 512);
  wtrans_k<<<(1024 * 512 + 255) / 256, 256, 0, stream>>>(w5, wT5, 1024, 512);
  wtrans_k<<<(1024 * 512 + 255) / 256, 256, 0, stream>>>(w6, wT6, 1024, 512);

  // conv stack in two batch-halves of 32; conv5/6 K-split for occupancy
  for (int h = 0; h < 2; ++h) {
    const float* xh = x + (size_t)h * HB_ * 105 * 5500;
    float* c6h = c6 + (size_t)h * HB_ * D_ * L_;
    conv1d_k<105,10,3, 64,35><<<dim3(29,1,HB_),256,0,stream>>>(xh,   wT1,b1, bufA, 5500,1831);
    conv1d_k< 64, 3,2,128,64><<<dim3(15,2,HB_),256,0,stream>>>(bufA, wT2,b2, bufB, 1831, 915);
    conv1d_k<128, 3,2,256,64><<<dim3( 8,4,HB_),256,0,stream>>>(bufB, wT3,b3, bufA,  915, 457);
    conv1d_k<256, 3,2,512,64><<<dim3( 4,8,HB_),256,0,stream>>>(bufA, wT4,b4, bufB,  457, 228);
    // conv5: 2-way K-split (cin 2x256). partials in bufA, reduce -> bufB
    convks_k<256,2,2,512,64,2><<<dim3(2,16,HB_),256,0,stream>>>(
        bufB, wT5, bufA, 228, 114, 512 * 228, 1867776);
    redbias_k<512,114,2><<<(1867776 + 255) / 256, 256, 0, stream>>>(
        bufA, b5, bufB, 1867776, 1867776);
    // conv6: 4-way K-split (cin 4x128). partials in bufA, reduce -> c6h
    convks_k<128,2,2,512,64,4><<<dim3(1,32,HB_),256,0,stream>>>(
        bufB, wT6, bufA, 114, 57, 512 * 114, 933888);
    redbias_k<512,57,4><<<(933888 + 255) / 256, 256, 0, stream>>>(
        bufA, b6, c6h, 933888, 933888);
  }

  transpose_k<<<dim3(16, B_), 256, 0, stream>>>(c6, xT);
  qkv3_k<<<dim3(24, B_), 256, 0, stream>>>(xT, wq, wk, wv, qb, kb, vb);
  cbprep_k<<<NC_, 64, 0, stream>>>(cbook, cbT, cnorm);
  attn_k<<<B_ * H_, 256, 0, stream>>>(qb, kb, vb, cat);
  outproj_k<<<dim3(4, B_), 256, 0, stream>>>(cat, wo, bo, yattn);

  itranspose_k<<<dim3(16, B_), 256, 0, stream>>>(yattn, yT);
  vqgemm_k<<<dim3(8, B_), 256, 0, stream>>>(yT, cbT, cnorm, pminb, pidxb);
  vqfin_k<<<B_ * L_, 64, 0, stream>>>(yattn, cbook, pminb, pidxb, zq, outIdx, lpart);
  loss_k<<<1, 256, 0, stream>>>(lpart, outLoss);
}